// Round 5
// baseline (4323.684 us; speedup 1.0000x reference)
//
#include <hip/hip_runtime.h>
#include <hip/hip_fp16.h>

constexpr float ALPHA = 0.9f;
constexpr float DT    = 0.1f;
constexpr int BB   = 256;   // batch
constexpr int NIN  = 784;
constexpr int NN   = 1024;
constexpr int LL   = 4;
constexpr int NOUT = 10;
constexpr int TT   = 100;
constexpr int KXP  = 832;   // xin K padded to multiple of 64
constexpr int NSTAGE = TT + LL - 1;  // 103
constexpr unsigned GRIDN = 128;

typedef _Float16 f16x8 __attribute__((ext_vector_type(8)));
typedef _Float16 f16x4 __attribute__((ext_vector_type(4)));
typedef float    f32x4 __attribute__((ext_vector_type(4)));

// async global->LDS, 16B per lane. LDS dst must be wave-uniform base (linear fill).
#define GLL16(g, l) __builtin_amdgcn_global_load_lds( \
    (const __attribute__((address_space(1))) unsigned int*)(g), \
    (__attribute__((address_space(3))) unsigned int*)(l), 16, 0, 0)

// ---------------- weight fp32 -> fp16 conversion ----------------
__global__ void wconv_kernel(const float* __restrict__ Wrec,
                             const float* __restrict__ Win,
                             _Float16* __restrict__ Wrec_h,
                             _Float16* __restrict__ Win_h) {
    size_t i = (size_t)blockIdx.x * blockDim.x + threadIdx.x;  // 0 .. 1048575
    float4 r = ((const float4*)Wrec)[i];
    float4 n = ((const float4*)Win)[i];
    f16x4 rh = {(_Float16)r.x, (_Float16)r.y, (_Float16)r.z, (_Float16)r.w};
    f16x4 nh = {(_Float16)n.x, (_Float16)n.y, (_Float16)n.z, (_Float16)n.w};
    ((f16x4*)Wrec_h)[i] = rh;
    ((f16x4*)Win_h)[i]  = nh;
}

// ---------------- X / Wi fp32 -> split fp16 (hi+lo), K padded to 832 ------
__global__ void prep_kernel(const float* __restrict__ X,
                            const float* __restrict__ Wi_w,
                            _Float16* __restrict__ Xh_hi, _Float16* __restrict__ Xh_lo,
                            _Float16* __restrict__ Wih_hi, _Float16* __restrict__ Wih_lo) {
    int row = blockIdx.x;  // 0..1279
    const float* src;
    _Float16 *dhi, *dlo;
    if (row < BB) {
        src = X + (size_t)row * NIN;
        dhi = Xh_hi + (size_t)row * KXP;  dlo = Xh_lo + (size_t)row * KXP;
    } else {
        int r = row - BB;
        src = Wi_w + (size_t)r * NIN;
        dhi = Wih_hi + (size_t)r * KXP;   dlo = Wih_lo + (size_t)r * KXP;
    }
    for (int k = threadIdx.x; k < KXP; k += 256) {
        float v = (k < NIN) ? src[k] : 0.f;
        _Float16 hi = (_Float16)v;
        dhi[k] = hi;
        dlo[k] = (_Float16)(v - (float)hi);
    }
}

// ---------------- combined bias: bc[l] = Wrec_b[l] (+ Win_b[l] for l>0) ----
__global__ void bias_kernel(const float* __restrict__ Win_b,
                            const float* __restrict__ Wrec_b,
                            float* __restrict__ bc) {
    int i = blockIdx.x * 256 + threadIdx.x;  // 0..4095
    int l = i >> 10;
    float v = Wrec_b[i];
    if (l > 0) v += Win_b[i];
    bc[i] = v;
}

// ---------------- x_in = X @ Wi_w^T + Wi_b, split-fp16 3-pass MFMA --------
// error ~1e-5: Ah@Bh + Ah@Bl + Al@Bh, fp32 accumulate. 32 blocks.
__global__ __launch_bounds__(256, 1) void xin_gemm(
    const _Float16* __restrict__ Xh_hi, const _Float16* __restrict__ Xh_lo,
    const _Float16* __restrict__ Wih_hi, const _Float16* __restrict__ Wih_lo,
    const float* __restrict__ Wi_b, float* __restrict__ x_in) {
    const int b = blockIdx.x;
    const int mt = b & 1, nt = b >> 1;
    const int row0 = mt * 128, col0 = nt * 64;

    const _Float16* Alist[3] = { Xh_hi + (size_t)row0 * KXP, Xh_hi + (size_t)row0 * KXP,
                                 Xh_lo + (size_t)row0 * KXP };
    const _Float16* Blist[3] = { Wih_hi + (size_t)col0 * KXP, Wih_lo + (size_t)col0 * KXP,
                                 Wih_hi + (size_t)col0 * KXP };

    __shared__ __align__(16) _Float16 ldsA[2][128 * 64];
    __shared__ __align__(16) _Float16 ldsB[2][64 * 64];

    const int tid = threadIdx.x;
    const int w = tid >> 6, lane = tid & 63;
    const int lm = lane & 15, kg = lane >> 4;
    const int rsub = lane >> 3, cch = lane & 7;
    const int wr = w >> 1, wc = w & 1;

    f32x4 acc[4][2] = {};
    constexpr int NIT = 3 * (KXP / 64);  // 39

    auto stage = [&](int kk, int buf) {
        int p = (kk >= 26) ? 2 : (kk >= 13 ? 1 : 0);
        int kw = (kk - p * 13) * 64;
        const _Float16* Ap = Alist[p];
        const _Float16* Bp = Blist[p];
        #pragma unroll
        for (int i = 0; i < 4; ++i) {
            const _Float16* g = Ap + (size_t)((w * 4 + i) * 8 + rsub) * KXP + kw + ((cch ^ rsub) * 8);
            GLL16(g, &ldsA[buf][(w * 4 + i) * 512]);
        }
        #pragma unroll
        for (int i = 0; i < 2; ++i) {
            const _Float16* g = Bp + (size_t)((w * 2 + i) * 8 + rsub) * KXP + kw + ((cch ^ rsub) * 8);
            GLL16(g, &ldsB[buf][(w * 2 + i) * 512]);
        }
    };

    stage(0, 0);
    __syncthreads();
    for (int kk = 0; kk < NIT; ++kk) {
        int cur = kk & 1;
        if (kk + 1 < NIT) stage(kk + 1, cur ^ 1);
        const _Float16* lA = ldsA[cur];
        const _Float16* lB = ldsB[cur];
        #pragma unroll
        for (int ks = 0; ks < 2; ++ks) {
            f16x8 a[4], bf[2];
            #pragma unroll
            for (int am = 0; am < 4; ++am) {
                int r = wr * 64 + am * 16 + lm;
                a[am] = *(const f16x8*)(lA + r * 64 + ((((ks << 2) | kg) ^ (lm & 7)) * 8));
            }
            #pragma unroll
            for (int bn = 0; bn < 2; ++bn) {
                int c = wc * 32 + bn * 16 + lm;
                bf[bn] = *(const f16x8*)(lB + c * 64 + ((((ks << 2) | kg) ^ (lm & 7)) * 8));
            }
            #pragma unroll
            for (int am = 0; am < 4; ++am)
                #pragma unroll
                for (int bn = 0; bn < 2; ++bn)
                    acc[am][bn] = __builtin_amdgcn_mfma_f32_16x16x32_f16(a[am], bf[bn], acc[am][bn], 0, 0, 0);
        }
        __syncthreads();
    }

    #pragma unroll
    for (int am = 0; am < 4; ++am)
        #pragma unroll
        for (int bn = 0; bn < 2; ++bn)
            #pragma unroll
            for (int r = 0; r < 4; ++r) {
                int row = row0 + wr * 64 + am * 16 + kg * 4 + r;
                int col = col0 + wc * 32 + bn * 16 + lm;
                x_in[(size_t)row * NN + col] = acc[am][bn][r] + Wi_b[col];
            }
}

// ---------------- hand-rolled grid barrier (per-stage slot, bounded spin) --
// Release fetch_add publishes this block's prior stores to agent scope
// (L2 writeback on gfx950); acquire spin-load invalidates stale caches.
// Spin is BOUNDED (~0.35s) so a logic error yields a wrong answer, not a hang.
__device__ __forceinline__ void grid_bar(unsigned* __restrict__ slot) {
    __syncthreads();
    if (threadIdx.x == 0) {
        __hip_atomic_fetch_add(slot, 1u, __ATOMIC_RELEASE, __HIP_MEMORY_SCOPE_AGENT);
        for (int it = 0; it < (1 << 20); ++it) {
            if (__hip_atomic_load(slot, __ATOMIC_ACQUIRE, __HIP_MEMORY_SCOPE_AGENT) >= GRIDN)
                break;
            __builtin_amdgcn_s_sleep(4);
        }
    }
    __syncthreads();
}

// ---------------- persistent wavefront kernel: all 103 stages -------------
// Hf: [4][256][1024] fp32 state (in-place), Hh: [2][4][256][1024] fp16 shadow.
// layer l at t=s-l: pre = h_l(t-1)@Wrec^T (+ h_{l-1}(t)@Win^T for l>0) + bias (+x_in l0)
__global__ __launch_bounds__(256, 1) void persist_kernel(
    const _Float16* __restrict__ Wrec_h,
    const _Float16* __restrict__ Win_h,
    const float* __restrict__ bc,
    const float* __restrict__ x_in,
    float* __restrict__ Hf,
    _Float16* __restrict__ Hh,
    unsigned* __restrict__ bar) {
    const int b = blockIdx.x;
    const int l = (b & 7) >> 1;               // layer -> XCD pair
    const int j = (b & 1) | ((b >> 3) << 1);  // 0..31 tile within layer
    const int mt = j & 1, nt = j >> 1;
    const int row0 = mt * 128, col0 = nt * 64;
    const size_t HSZ = (size_t)BB * NN;

    __shared__ __align__(16) _Float16 ldsA[2][128 * 64];
    __shared__ __align__(16) _Float16 ldsB[2][64 * 64];

    const int tid = threadIdx.x;
    const int w = tid >> 6, lane = tid & 63;
    const int lm = lane & 15, kg = lane >> 4;
    const int rsub = lane >> 3, cch = lane & 7;
    const int wr = w >> 1, wc = w & 1;

    const _Float16* WrB = Wrec_h + (size_t)l * NN * NN + (size_t)col0 * NN;
    const _Float16* WnB = Win_h  + (size_t)l * NN * NN + (size_t)col0 * NN;
    const float* bcl = bc + l * NN;
    float* Hfl = Hf + (size_t)l * HSZ;

    for (int s = 0; s < NSTAGE; ++s) {
        const int t = s - l;
        if (t >= 0 && t < TT) {
            const int src = t & 1, dst = src ^ 1;
            const _Float16* A0 = Hh + ((size_t)src * LL + l) * HSZ + (size_t)row0 * NN;
            const _Float16* A1 = (l > 0)
                ? Hh + ((size_t)dst * LL + (l - 1)) * HSZ + (size_t)row0 * NN : A0;
            const int niter = (l > 0) ? 32 : 16;

            f32x4 acc[4][2] = {};

            auto stage = [&](int kk, int buf) {
                const _Float16 *Ap, *Bp;
                int kw;
                if (kk < 16) { Ap = A0; Bp = WrB; kw = kk * 64; }
                else         { Ap = A1; Bp = WnB; kw = (kk - 16) * 64; }
                #pragma unroll
                for (int i = 0; i < 4; ++i) {
                    const _Float16* g = Ap + (size_t)((w * 4 + i) * 8 + rsub) * NN + kw + ((cch ^ rsub) * 8);
                    GLL16(g, &ldsA[buf][(w * 4 + i) * 512]);
                }
                #pragma unroll
                for (int i = 0; i < 2; ++i) {
                    const _Float16* g = Bp + (size_t)((w * 2 + i) * 8 + rsub) * NN + kw + ((cch ^ rsub) * 8);
                    GLL16(g, &ldsB[buf][(w * 2 + i) * 512]);
                }
            };

            stage(0, 0);
            __syncthreads();
            for (int kk = 0; kk < niter; ++kk) {
                int cur = kk & 1;
                if (kk + 1 < niter) stage(kk + 1, cur ^ 1);
                const _Float16* lA = ldsA[cur];
                const _Float16* lB = ldsB[cur];
                #pragma unroll
                for (int ks = 0; ks < 2; ++ks) {
                    f16x8 a[4], bf[2];
                    #pragma unroll
                    for (int am = 0; am < 4; ++am) {
                        int r = wr * 64 + am * 16 + lm;
                        a[am] = *(const f16x8*)(lA + r * 64 + ((((ks << 2) | kg) ^ (lm & 7)) * 8));
                    }
                    #pragma unroll
                    for (int bn = 0; bn < 2; ++bn) {
                        int c = wc * 32 + bn * 16 + lm;
                        bf[bn] = *(const f16x8*)(lB + c * 64 + ((((ks << 2) | kg) ^ (lm & 7)) * 8));
                    }
                    #pragma unroll
                    for (int am = 0; am < 4; ++am)
                        #pragma unroll
                        for (int bn = 0; bn < 2; ++bn)
                            acc[am][bn] = __builtin_amdgcn_mfma_f32_16x16x32_f16(a[am], bf[bn], acc[am][bn], 0, 0, 0);
                }
                __syncthreads();
            }

            // epilogue: h' = h + DT*(-ALPHA*h + sin(pre))
            _Float16* Hhd = Hh + ((size_t)dst * LL + l) * HSZ;
            #pragma unroll
            for (int am = 0; am < 4; ++am)
                #pragma unroll
                for (int bn = 0; bn < 2; ++bn)
                    #pragma unroll
                    for (int r = 0; r < 4; ++r) {
                        int row = row0 + wr * 64 + am * 16 + kg * 4 + r;
                        int col = col0 + wc * 32 + bn * 16 + lm;
                        size_t idx = (size_t)row * NN + col;
                        float pre = acc[am][bn][r] + bcl[col];
                        if (l == 0) pre += x_in[idx];
                        float hold = Hfl[idx];
                        float hnew = hold + DT * (-ALPHA * hold + __sinf(pre));
                        Hfl[idx] = hnew;
                        Hhd[idx] = (_Float16)hnew;
                    }
        }
        if (s < NSTAGE - 1) grid_bar(bar + s);
    }
}

// ---------------- out = h[3] @ Wo^T + Wo_b  (fp32) ----------------
__global__ __launch_bounds__(256) void out_kernel(
    const float* __restrict__ Hf, const float* __restrict__ Wo_w,
    const float* __restrict__ Wo_b, float* __restrict__ out) {
    const int r = blockIdx.x, tid = threadIdx.x;
    const int lane = tid & 63, w = tid >> 6;
    const float* h = Hf + (size_t)3 * BB * NN + (size_t)r * NN;
    float4 h4 = ((const float4*)h)[tid];
    __shared__ float red[4][16];
    #pragma unroll
    for (int jo = 0; jo < NOUT; ++jo) {
        float4 w4 = ((const float4*)(Wo_w + (size_t)jo * NN))[tid];
        float p = h4.x * w4.x + h4.y * w4.y + h4.z * w4.z + h4.w * w4.w;
        #pragma unroll
        for (int off = 32; off; off >>= 1) p += __shfl_down(p, off);
        if (lane == 0) red[w][jo] = p;
    }
    __syncthreads();
    if (tid < NOUT)
        out[r * NOUT + tid] = red[0][tid] + red[1][tid] + red[2][tid] + red[3][tid] + Wo_b[tid];
}

extern "C" void kernel_launch(void* const* d_in, const int* in_sizes, int n_in,
                              void* d_out, int out_size, void* d_ws, size_t ws_size,
                              hipStream_t stream) {
    const float* X      = (const float*)d_in[0];
    const float* Wi_w   = (const float*)d_in[1];
    const float* Wi_b   = (const float*)d_in[2];
    const float* Win_w  = (const float*)d_in[3];
    const float* Win_b  = (const float*)d_in[4];
    const float* Wrec_w = (const float*)d_in[5];
    const float* Wrec_b = (const float*)d_in[6];
    const float* Wo_w   = (const float*)d_in[7];
    const float* Wo_b   = (const float*)d_in[8];

    char* ws = (char*)d_ws;
    _Float16* Wrec_h = (_Float16*)(ws);                                  // 8 MiB
    _Float16* Win_h  = (_Float16*)(ws + (size_t)(8u  << 20));            // 8 MiB
    float*    Hf     = (float*)   (ws + (size_t)(16u << 20));            // 4 MiB
    _Float16* Hh     = (_Float16*)(ws + (size_t)(20u << 20));            // 4 MiB
    float*    x_in   = (float*)   (ws + (size_t)(24u << 20));            // 1 MiB
    float*    bc     = (float*)   (ws + (size_t)(25u << 20));            // 16 KiB
    _Float16* Xh_hi  = (_Float16*)(ws + (size_t)(25u << 20) + (64u << 10));   // 416 KiB
    _Float16* Xh_lo  = (_Float16*)(ws + (size_t)(25u << 20) + (576u << 10));  // 416 KiB
    unsigned* bar    = (unsigned*)(ws + (size_t)(26u << 20));            // 512 B
    // Wih hi/lo temporarily alias the Hh region (3.25 MiB <= 4 MiB); used only
    // by prep/xin_gemm; Hh parity-0 is memset before persist_kernel, and
    // parity-1 leftover bytes are always written (as dst) before first read.
    _Float16* Wih_hi = (_Float16*)(ws + (size_t)(20u << 20));
    _Float16* Wih_lo = Wih_hi + (size_t)NN * KXP;

    wconv_kernel<<<4096, 256, 0, stream>>>(Wrec_w, Win_w, Wrec_h, Win_h);
    prep_kernel<<<BB + NN, 256, 0, stream>>>(X, Wi_w, Xh_hi, Xh_lo, Wih_hi, Wih_lo);
    bias_kernel<<<16, 256, 0, stream>>>(Win_b, Wrec_b, bc);
    xin_gemm<<<32, 256, 0, stream>>>(Xh_hi, Xh_lo, Wih_hi, Wih_lo, Wi_b, x_in);

    hipMemsetAsync(Hf, 0, (size_t)LL * BB * NN * sizeof(float), stream);
    hipMemsetAsync(Hh, 0, (size_t)LL * BB * NN * sizeof(_Float16), stream);  // parity 0
    hipMemsetAsync(bar, 0, NSTAGE * sizeof(unsigned), stream);

    persist_kernel<<<GRIDN, 256, 0, stream>>>(Wrec_h, Win_h, bc, x_in, Hf, Hh, bar);

    out_kernel<<<BB, 256, 0, stream>>>(Hf, Wo_w, Wo_b, (float*)d_out);
}

// Round 6
// 4245.137 us; speedup vs baseline: 1.0185x; 1.0185x over previous
//
#include <hip/hip_runtime.h>
#include <hip/hip_fp16.h>

constexpr float ALPHA = 0.9f;
constexpr float DT    = 0.1f;
constexpr int BB   = 256;   // batch
constexpr int NIN  = 784;
constexpr int NN   = 1024;
constexpr int LL   = 4;
constexpr int NOUT = 10;
constexpr int TT   = 100;
constexpr int KXP  = 832;   // xin K padded to multiple of 64
constexpr int NSTAGE = TT + LL - 1;  // 103
constexpr unsigned GRIDN = 256;
constexpr unsigned GRPSZ = 32;       // blocks per b&7 group (same XCD)

typedef _Float16 f16x8 __attribute__((ext_vector_type(8)));
typedef _Float16 f16x4 __attribute__((ext_vector_type(4)));
typedef float    f32x4 __attribute__((ext_vector_type(4)));

// async global->LDS, 16B per lane. LDS dst must be wave-uniform base (linear fill).
#define GLL16(g, l) __builtin_amdgcn_global_load_lds( \
    (const __attribute__((address_space(1))) unsigned int*)(g), \
    (__attribute__((address_space(3))) unsigned int*)(l), 16, 0, 0)

#define VMCNT(n) asm volatile("s_waitcnt vmcnt(" #n ")" ::: "memory")

// ---------------- weight fp32 -> fp16 conversion ----------------
__global__ void wconv_kernel(const float* __restrict__ Wrec,
                             const float* __restrict__ Win,
                             _Float16* __restrict__ Wrec_h,
                             _Float16* __restrict__ Win_h) {
    size_t i = (size_t)blockIdx.x * blockDim.x + threadIdx.x;  // 0 .. 1048575
    float4 r = ((const float4*)Wrec)[i];
    float4 n = ((const float4*)Win)[i];
    f16x4 rh = {(_Float16)r.x, (_Float16)r.y, (_Float16)r.z, (_Float16)r.w};
    f16x4 nh = {(_Float16)n.x, (_Float16)n.y, (_Float16)n.z, (_Float16)n.w};
    ((f16x4*)Wrec_h)[i] = rh;
    ((f16x4*)Win_h)[i]  = nh;
}

// ---------------- X / Wi fp32 -> split fp16 (hi+lo), K padded to 832 ------
__global__ void prep_kernel(const float* __restrict__ X,
                            const float* __restrict__ Wi_w,
                            _Float16* __restrict__ Xh_hi, _Float16* __restrict__ Xh_lo,
                            _Float16* __restrict__ Wih_hi, _Float16* __restrict__ Wih_lo) {
    int row = blockIdx.x;  // 0..1279
    const float* src;
    _Float16 *dhi, *dlo;
    if (row < BB) {
        src = X + (size_t)row * NIN;
        dhi = Xh_hi + (size_t)row * KXP;  dlo = Xh_lo + (size_t)row * KXP;
    } else {
        int r = row - BB;
        src = Wi_w + (size_t)r * NIN;
        dhi = Wih_hi + (size_t)r * KXP;   dlo = Wih_lo + (size_t)r * KXP;
    }
    for (int k = threadIdx.x; k < KXP; k += 256) {
        float v = (k < NIN) ? src[k] : 0.f;
        _Float16 hi = (_Float16)v;
        dhi[k] = hi;
        dlo[k] = (_Float16)(v - (float)hi);
    }
}

// ---------------- combined bias: bc[l] = Wrec_b[l] (+ Win_b[l] for l>0) ----
__global__ void bias_kernel(const float* __restrict__ Win_b,
                            const float* __restrict__ Wrec_b,
                            float* __restrict__ bc) {
    int i = blockIdx.x * 256 + threadIdx.x;  // 0..4095
    int l = i >> 10;
    float v = Wrec_b[i];
    if (l > 0) v += Win_b[i];
    bc[i] = v;
}

// ---------------- x_in = X @ Wi_w^T + Wi_b, split-fp16 3-pass MFMA --------
// error ~1e-5: Ah@Bh + Ah@Bl + Al@Bh, fp32 accumulate. 32 blocks.
__global__ __launch_bounds__(256, 1) void xin_gemm(
    const _Float16* __restrict__ Xh_hi, const _Float16* __restrict__ Xh_lo,
    const _Float16* __restrict__ Wih_hi, const _Float16* __restrict__ Wih_lo,
    const float* __restrict__ Wi_b, float* __restrict__ x_in) {
    const int b = blockIdx.x;
    const int mt = b & 1, nt = b >> 1;
    const int row0 = mt * 128, col0 = nt * 64;

    const _Float16* Alist[3] = { Xh_hi + (size_t)row0 * KXP, Xh_hi + (size_t)row0 * KXP,
                                 Xh_lo + (size_t)row0 * KXP };
    const _Float16* Blist[3] = { Wih_hi + (size_t)col0 * KXP, Wih_lo + (size_t)col0 * KXP,
                                 Wih_hi + (size_t)col0 * KXP };

    __shared__ __align__(16) _Float16 ldsA[2][128 * 64];
    __shared__ __align__(16) _Float16 ldsB[2][64 * 64];

    const int tid = threadIdx.x;
    const int w = tid >> 6, lane = tid & 63;
    const int lm = lane & 15, kg = lane >> 4;
    const int rsub = lane >> 3, cch = lane & 7;
    const int wr = w >> 1, wc = w & 1;

    f32x4 acc[4][2] = {};
    constexpr int NIT = 3 * (KXP / 64);  // 39

    auto stage = [&](int kk, int buf) {
        int p = (kk >= 26) ? 2 : (kk >= 13 ? 1 : 0);
        int kw = (kk - p * 13) * 64;
        const _Float16* Ap = Alist[p];
        const _Float16* Bp = Blist[p];
        #pragma unroll
        for (int i = 0; i < 4; ++i) {
            const _Float16* g = Ap + (size_t)((w * 4 + i) * 8 + rsub) * KXP + kw + ((cch ^ rsub) * 8);
            GLL16(g, &ldsA[buf][(w * 4 + i) * 512]);
        }
        #pragma unroll
        for (int i = 0; i < 2; ++i) {
            const _Float16* g = Bp + (size_t)((w * 2 + i) * 8 + rsub) * KXP + kw + ((cch ^ rsub) * 8);
            GLL16(g, &ldsB[buf][(w * 2 + i) * 512]);
        }
    };

    stage(0, 0);
    __syncthreads();
    for (int kk = 0; kk < NIT; ++kk) {
        int cur = kk & 1;
        if (kk + 1 < NIT) stage(kk + 1, cur ^ 1);
        const _Float16* lA = ldsA[cur];
        const _Float16* lB = ldsB[cur];
        #pragma unroll
        for (int ks = 0; ks < 2; ++ks) {
            f16x8 a[4], bf[2];
            #pragma unroll
            for (int am = 0; am < 4; ++am) {
                int r = wr * 64 + am * 16 + lm;
                a[am] = *(const f16x8*)(lA + r * 64 + ((((ks << 2) | kg) ^ (lm & 7)) * 8));
            }
            #pragma unroll
            for (int bn = 0; bn < 2; ++bn) {
                int c = wc * 32 + bn * 16 + lm;
                bf[bn] = *(const f16x8*)(lB + c * 64 + ((((ks << 2) | kg) ^ (lm & 7)) * 8));
            }
            #pragma unroll
            for (int am = 0; am < 4; ++am)
                #pragma unroll
                for (int bn = 0; bn < 2; ++bn)
                    acc[am][bn] = __builtin_amdgcn_mfma_f32_16x16x32_f16(a[am], bf[bn], acc[am][bn], 0, 0, 0);
        }
        __syncthreads();
    }

    #pragma unroll
    for (int am = 0; am < 4; ++am)
        #pragma unroll
        for (int bn = 0; bn < 2; ++bn)
            #pragma unroll
            for (int r = 0; r < 4; ++r) {
                int row = row0 + wr * 64 + am * 16 + kg * 4 + r;
                int col = col0 + wc * 32 + bn * 16 + lm;
                x_in[(size_t)row * NN + col] = acc[am][bn][r] + Wi_b[col];
            }
}

// ---------------- 2-level grid barrier, relaxed spin, one acquire ----------
// Layout per stage: base[0..7]=group counters, base[8]=root, base[15]=flag.
// Chain: member ACQ_REL->gcnt; group-last ACQ_REL->root; root-last REL->flag;
// spinners RELAXED-poll flag, then one ACQUIRE load (single cache-inv/stage).
__device__ __forceinline__ void grid_bar(unsigned* base) {
    __syncthreads();
    if (threadIdx.x == 0) {
        unsigned* flag = base + 15;
        unsigned pg = __hip_atomic_fetch_add(base + (blockIdx.x & 7), 1u,
                                             __ATOMIC_ACQ_REL, __HIP_MEMORY_SCOPE_AGENT);
        if (pg == GRPSZ - 1) {
            unsigned pr = __hip_atomic_fetch_add(base + 8, 1u,
                                                 __ATOMIC_ACQ_REL, __HIP_MEMORY_SCOPE_AGENT);
            if (pr == 7)
                __hip_atomic_store(flag, 1u, __ATOMIC_RELEASE, __HIP_MEMORY_SCOPE_AGENT);
        }
        for (int it = 0; it < (1 << 20); ++it) {  // bounded: wrong answer, not hang
            if (__hip_atomic_load(flag, __ATOMIC_RELAXED, __HIP_MEMORY_SCOPE_AGENT)) break;
            __builtin_amdgcn_s_sleep(2);
        }
        (void)__hip_atomic_load(flag, __ATOMIC_ACQUIRE, __HIP_MEMORY_SCOPE_AGENT);
    }
    __syncthreads();
}

// ---------------- persistent wavefront kernel: all 103 stages -------------
// Hf: [4][256][1024] fp32 state (in-place), Hh: [2][4][256][1024] fp16 shadow.
// 256 blocks = 4 layers x (2 mt x 32 nt); BM=128, BN=32, BK=64.
// K-loop: T4 counted-vmcnt pipeline (raw s_barrier, vmcnt(5) not 0).
__global__ __launch_bounds__(256, 1) void persist_kernel(
    const _Float16* __restrict__ Wrec_h,
    const _Float16* __restrict__ Win_h,
    const float* __restrict__ bc,
    const float* __restrict__ x_in,
    float* __restrict__ Hf,
    _Float16* __restrict__ Hh,
    unsigned* __restrict__ bar) {
    const int b = blockIdx.x;
    const int l  = (b & 7) >> 1;   // layer -> XCD pair (b%8 heuristic)
    const int mt = b & 1;          // M-tile -> fixed XCD within pair (A-panel L2 share)
    const int nt = b >> 3;         // 0..31 N-tile
    const int row0 = mt * 128, col0 = nt * 32;
    const size_t HSZ = (size_t)BB * NN;

    __shared__ __align__(16) _Float16 ldsA[2][128 * 64];  // 32 KiB
    __shared__ __align__(16) _Float16 ldsB[2][32 * 64];   // 8 KiB

    const int tid = threadIdx.x;
    const int w = tid >> 6, lane = tid & 63;
    const int lm = lane & 15, kg = lane >> 4;
    const int rsub = lane >> 3, cch = lane & 7;
    const int wr = w >> 1, wc = w & 1;

    const _Float16* WrB = Wrec_h + (size_t)l * NN * NN + (size_t)col0 * NN;
    const _Float16* WnB = Win_h  + (size_t)l * NN * NN + (size_t)col0 * NN;
    const float* bcl = bc + l * NN;
    float* Hfl = Hf + (size_t)l * HSZ;

    for (int s = 0; s < NSTAGE; ++s) {
        const int t = s - l;
        if (t >= 0 && t < TT) {
            const int src = t & 1, dst = src ^ 1;
            const _Float16* A0 = Hh + ((size_t)src * LL + l) * HSZ + (size_t)row0 * NN;
            const _Float16* A1 = (l > 0)
                ? Hh + ((size_t)dst * LL + (l - 1)) * HSZ + (size_t)row0 * NN : A0;
            const int niter = (l > 0) ? 32 : 16;

            f32x4 acc[4] = {};

            // 5 global_load_lds per wave per K-step (A:4, B:1)
            auto stage = [&](int kk, int buf) {
                const _Float16 *Ap, *Bp;
                int kw;
                if (kk < 16) { Ap = A0; Bp = WrB; kw = kk * 64; }
                else         { Ap = A1; Bp = WnB; kw = (kk - 16) * 64; }
                #pragma unroll
                for (int i = 0; i < 4; ++i) {
                    const _Float16* g = Ap + (size_t)((w * 4 + i) * 8 + rsub) * NN + kw + ((cch ^ rsub) * 8);
                    GLL16(g, &ldsA[buf][(w * 4 + i) * 512]);
                }
                {
                    const _Float16* g = Bp + (size_t)(w * 8 + rsub) * NN + kw + ((cch ^ rsub) * 8);
                    GLL16(g, &ldsB[buf][w * 512]);
                }
            };

            stage(0, 0);
            for (int kk = 0; kk < niter; ++kk) {
                const int cur = kk & 1;
                if (kk + 1 < niter) {
                    stage(kk + 1, cur ^ 1);
                    VMCNT(5);            // wait cur's 5 loads; next 5 stay in flight
                } else {
                    VMCNT(0);
                }
                __builtin_amdgcn_s_barrier();
                __builtin_amdgcn_sched_barrier(0);
                const _Float16* lA = ldsA[cur];
                const _Float16* lB = ldsB[cur];
                #pragma unroll
                for (int ks = 0; ks < 2; ++ks) {
                    f16x8 a[4], bf;
                    #pragma unroll
                    for (int am = 0; am < 4; ++am) {
                        int r = wr * 64 + am * 16 + lm;
                        a[am] = *(const f16x8*)(lA + r * 64 + ((((ks << 2) | kg) ^ (lm & 7)) * 8));
                    }
                    {
                        int c = wc * 16 + lm;
                        bf = *(const f16x8*)(lB + c * 64 + ((((ks << 2) | kg) ^ (lm & 7)) * 8));
                    }
                    #pragma unroll
                    for (int am = 0; am < 4; ++am)
                        acc[am] = __builtin_amdgcn_mfma_f32_16x16x32_f16(a[am], bf, acc[am], 0, 0, 0);
                }
                __builtin_amdgcn_sched_barrier(0);
                __builtin_amdgcn_s_barrier();
            }

            // epilogue: h' = h + DT*(-ALPHA*h + sin(pre))
            _Float16* Hhd = Hh + ((size_t)dst * LL + l) * HSZ;
            #pragma unroll
            for (int am = 0; am < 4; ++am)
                #pragma unroll
                for (int r = 0; r < 4; ++r) {
                    int row = row0 + wr * 64 + am * 16 + kg * 4 + r;
                    int col = col0 + wc * 16 + lm;
                    size_t idx = (size_t)row * NN + col;
                    float pre = acc[am][r] + bcl[col];
                    if (l == 0) pre += x_in[idx];
                    float hold = Hfl[idx];
                    float hnew = hold + DT * (-ALPHA * hold + __sinf(pre));
                    Hfl[idx] = hnew;
                    Hhd[idx] = (_Float16)hnew;
                }
        }
        if (s < NSTAGE - 1) grid_bar(bar + s * 16);
    }
}

// ---------------- out = h[3] @ Wo^T + Wo_b  (fp32) ----------------
__global__ __launch_bounds__(256) void out_kernel(
    const float* __restrict__ Hf, const float* __restrict__ Wo_w,
    const float* __restrict__ Wo_b, float* __restrict__ out) {
    const int r = blockIdx.x, tid = threadIdx.x;
    const int lane = tid & 63, w = tid >> 6;
    const float* h = Hf + (size_t)3 * BB * NN + (size_t)r * NN;
    float4 h4 = ((const float4*)h)[tid];
    __shared__ float red[4][16];
    #pragma unroll
    for (int jo = 0; jo < NOUT; ++jo) {
        float4 w4 = ((const float4*)(Wo_w + (size_t)jo * NN))[tid];
        float p = h4.x * w4.x + h4.y * w4.y + h4.z * w4.z + h4.w * w4.w;
        #pragma unroll
        for (int off = 32; off; off >>= 1) p += __shfl_down(p, off);
        if (lane == 0) red[w][jo] = p;
    }
    __syncthreads();
    if (tid < NOUT)
        out[r * NOUT + tid] = red[0][tid] + red[1][tid] + red[2][tid] + red[3][tid] + Wo_b[tid];
}

extern "C" void kernel_launch(void* const* d_in, const int* in_sizes, int n_in,
                              void* d_out, int out_size, void* d_ws, size_t ws_size,
                              hipStream_t stream) {
    const float* X      = (const float*)d_in[0];
    const float* Wi_w   = (const float*)d_in[1];
    const float* Wi_b   = (const float*)d_in[2];
    const float* Win_w  = (const float*)d_in[3];
    const float* Win_b  = (const float*)d_in[4];
    const float* Wrec_w = (const float*)d_in[5];
    const float* Wrec_b = (const float*)d_in[6];
    const float* Wo_w   = (const float*)d_in[7];
    const float* Wo_b   = (const float*)d_in[8];

    char* ws = (char*)d_ws;
    _Float16* Wrec_h = (_Float16*)(ws);                                  // 8 MiB
    _Float16* Win_h  = (_Float16*)(ws + (size_t)(8u  << 20));            // 8 MiB
    float*    Hf     = (float*)   (ws + (size_t)(16u << 20));            // 4 MiB
    _Float16* Hh     = (_Float16*)(ws + (size_t)(20u << 20));            // 4 MiB
    float*    x_in   = (float*)   (ws + (size_t)(24u << 20));            // 1 MiB
    float*    bc     = (float*)   (ws + (size_t)(25u << 20));            // 16 KiB
    _Float16* Xh_hi  = (_Float16*)(ws + (size_t)(25u << 20) + (64u << 10));   // 416 KiB
    _Float16* Xh_lo  = (_Float16*)(ws + (size_t)(25u << 20) + (576u << 10));  // 416 KiB
    unsigned* bar    = (unsigned*)(ws + (size_t)(26u << 20));            // 6.6 KiB
    // Wih hi/lo temporarily alias the Hh region (3.25 MiB <= 4 MiB); used only
    // by prep/xin_gemm; Hh parity-0 is memset before persist_kernel, and
    // parity-1 leftover bytes are always written (as dst) before first read.
    _Float16* Wih_hi = (_Float16*)(ws + (size_t)(20u << 20));
    _Float16* Wih_lo = Wih_hi + (size_t)NN * KXP;

    wconv_kernel<<<4096, 256, 0, stream>>>(Wrec_w, Win_w, Wrec_h, Win_h);
    prep_kernel<<<BB + NN, 256, 0, stream>>>(X, Wi_w, Xh_hi, Xh_lo, Wih_hi, Wih_lo);
    bias_kernel<<<16, 256, 0, stream>>>(Win_b, Wrec_b, bc);
    xin_gemm<<<32, 256, 0, stream>>>(Xh_hi, Xh_lo, Wih_hi, Wih_lo, Wi_b, x_in);

    hipMemsetAsync(Hf, 0, (size_t)LL * BB * NN * sizeof(float), stream);
    hipMemsetAsync(Hh, 0, (size_t)LL * BB * NN * sizeof(_Float16), stream);  // parity 0
    hipMemsetAsync(bar, 0, NSTAGE * 16 * sizeof(unsigned), stream);

    persist_kernel<<<GRIDN, 256, 0, stream>>>(Wrec_h, Win_h, bc, x_in, Hf, Hh, bar);

    out_kernel<<<BB, 256, 0, stream>>>(Hf, Wo_w, Wo_b, (float*)d_out);
}

// Round 7
// 2426.818 us; speedup vs baseline: 1.7816x; 1.7493x over previous
//
#include <hip/hip_runtime.h>
#include <hip/hip_fp16.h>

constexpr float ALPHA = 0.9f;
constexpr float DT    = 0.1f;
constexpr int BB   = 256;   // batch
constexpr int NIN  = 784;
constexpr int NN   = 1024;
constexpr int LL   = 4;
constexpr int NOUT = 10;
constexpr int TT   = 100;
constexpr int KXP  = 832;   // xin K padded to multiple of 64
constexpr int NSTAGE = TT + LL - 1;  // 103
constexpr unsigned GRIDN = 256;
constexpr unsigned GRPSZ = 32;       // blocks per b&7 group (same XCD)
constexpr int NC = 32;               // K chunks of 32 per GEMM

typedef _Float16 f16x8 __attribute__((ext_vector_type(8)));
typedef _Float16 f16x4 __attribute__((ext_vector_type(4)));
typedef float    f32x4 __attribute__((ext_vector_type(4)));

// async global->LDS, 16B per lane. LDS dst must be wave-uniform base (linear fill).
#define GLL16(g, l) __builtin_amdgcn_global_load_lds( \
    (const __attribute__((address_space(1))) unsigned int*)(g), \
    (__attribute__((address_space(3))) unsigned int*)(l), 16, 0, 0)

#define VMCNT(n) asm volatile("s_waitcnt vmcnt(" #n ")" ::: "memory")

// ---------------- weight fp32 -> fp16 conversion ----------------
__global__ void wconv_kernel(const float* __restrict__ Wrec,
                             const float* __restrict__ Win,
                             _Float16* __restrict__ Wrec_h,
                             _Float16* __restrict__ Win_h) {
    size_t i = (size_t)blockIdx.x * blockDim.x + threadIdx.x;  // 0 .. 1048575
    float4 r = ((const float4*)Wrec)[i];
    float4 n = ((const float4*)Win)[i];
    f16x4 rh = {(_Float16)r.x, (_Float16)r.y, (_Float16)r.z, (_Float16)r.w};
    f16x4 nh = {(_Float16)n.x, (_Float16)n.y, (_Float16)n.z, (_Float16)n.w};
    ((f16x4*)Wrec_h)[i] = rh;
    ((f16x4*)Win_h)[i]  = nh;
}

// ---------------- X / Wi fp32 -> split fp16 (hi+lo), K padded to 832 ------
__global__ void prep_kernel(const float* __restrict__ X,
                            const float* __restrict__ Wi_w,
                            _Float16* __restrict__ Xh_hi, _Float16* __restrict__ Xh_lo,
                            _Float16* __restrict__ Wih_hi, _Float16* __restrict__ Wih_lo) {
    int row = blockIdx.x;  // 0..1279
    const float* src;
    _Float16 *dhi, *dlo;
    if (row < BB) {
        src = X + (size_t)row * NIN;
        dhi = Xh_hi + (size_t)row * KXP;  dlo = Xh_lo + (size_t)row * KXP;
    } else {
        int r = row - BB;
        src = Wi_w + (size_t)r * NIN;
        dhi = Wih_hi + (size_t)r * KXP;   dlo = Wih_lo + (size_t)r * KXP;
    }
    for (int k = threadIdx.x; k < KXP; k += 256) {
        float v = (k < NIN) ? src[k] : 0.f;
        _Float16 hi = (_Float16)v;
        dhi[k] = hi;
        dlo[k] = (_Float16)(v - (float)hi);
    }
}

// ---------------- combined bias: bc[l] = Wrec_b[l] (+ Win_b[l] for l>0) ----
__global__ void bias_kernel(const float* __restrict__ Win_b,
                            const float* __restrict__ Wrec_b,
                            float* __restrict__ bc) {
    int i = blockIdx.x * 256 + threadIdx.x;  // 0..4095
    int l = i >> 10;
    float v = Wrec_b[i];
    if (l > 0) v += Win_b[i];
    bc[i] = v;
}

// ---------------- x_in = X @ Wi_w^T + Wi_b, split-fp16 3-pass MFMA --------
__global__ __launch_bounds__(256, 1) void xin_gemm(
    const _Float16* __restrict__ Xh_hi, const _Float16* __restrict__ Xh_lo,
    const _Float16* __restrict__ Wih_hi, const _Float16* __restrict__ Wih_lo,
    const float* __restrict__ Wi_b, float* __restrict__ x_in) {
    const int b = blockIdx.x;
    const int mt = b & 1, nt = b >> 1;
    const int row0 = mt * 128, col0 = nt * 64;

    const _Float16* Alist[3] = { Xh_hi + (size_t)row0 * KXP, Xh_hi + (size_t)row0 * KXP,
                                 Xh_lo + (size_t)row0 * KXP };
    const _Float16* Blist[3] = { Wih_hi + (size_t)col0 * KXP, Wih_lo + (size_t)col0 * KXP,
                                 Wih_hi + (size_t)col0 * KXP };

    __shared__ __align__(16) _Float16 ldsA[2][128 * 64];
    __shared__ __align__(16) _Float16 ldsB[2][64 * 64];

    const int tid = threadIdx.x;
    const int w = tid >> 6, lane = tid & 63;
    const int lm = lane & 15, kg = lane >> 4;
    const int rsub = lane >> 3, cch = lane & 7;
    const int wr = w >> 1, wc = w & 1;

    f32x4 acc[4][2] = {};
    constexpr int NIT = 3 * (KXP / 64);  // 39

    auto stage = [&](int kk, int buf) {
        int p = (kk >= 26) ? 2 : (kk >= 13 ? 1 : 0);
        int kw = (kk - p * 13) * 64;
        const _Float16* Ap = Alist[p];
        const _Float16* Bp = Blist[p];
        #pragma unroll
        for (int i = 0; i < 4; ++i) {
            const _Float16* g = Ap + (size_t)((w * 4 + i) * 8 + rsub) * KXP + kw + ((cch ^ rsub) * 8);
            GLL16(g, &ldsA[buf][(w * 4 + i) * 512]);
        }
        #pragma unroll
        for (int i = 0; i < 2; ++i) {
            const _Float16* g = Bp + (size_t)((w * 2 + i) * 8 + rsub) * KXP + kw + ((cch ^ rsub) * 8);
            GLL16(g, &ldsB[buf][(w * 2 + i) * 512]);
        }
    };

    stage(0, 0);
    __syncthreads();
    for (int kk = 0; kk < NIT; ++kk) {
        int cur = kk & 1;
        if (kk + 1 < NIT) stage(kk + 1, cur ^ 1);
        const _Float16* lA = ldsA[cur];
        const _Float16* lB = ldsB[cur];
        #pragma unroll
        for (int ks = 0; ks < 2; ++ks) {
            f16x8 a[4], bf[2];
            #pragma unroll
            for (int am = 0; am < 4; ++am) {
                int r = wr * 64 + am * 16 + lm;
                a[am] = *(const f16x8*)(lA + r * 64 + ((((ks << 2) | kg) ^ (lm & 7)) * 8));
            }
            #pragma unroll
            for (int bn = 0; bn < 2; ++bn) {
                int c = wc * 32 + bn * 16 + lm;
                bf[bn] = *(const f16x8*)(lB + c * 64 + ((((ks << 2) | kg) ^ (lm & 7)) * 8));
            }
            #pragma unroll
            for (int am = 0; am < 4; ++am)
                #pragma unroll
                for (int bn = 0; bn < 2; ++bn)
                    acc[am][bn] = __builtin_amdgcn_mfma_f32_16x16x32_f16(a[am], bf[bn], acc[am][bn], 0, 0, 0);
        }
        __syncthreads();
    }

    #pragma unroll
    for (int am = 0; am < 4; ++am)
        #pragma unroll
        for (int bn = 0; bn < 2; ++bn)
            #pragma unroll
            for (int r = 0; r < 4; ++r) {
                int row = row0 + wr * 64 + am * 16 + kg * 4 + r;
                int col = col0 + wc * 32 + bn * 16 + lm;
                x_in[(size_t)row * NN + col] = acc[am][bn][r] + Wi_b[col];
            }
}

// ---------------- 2-level grid barrier, relaxed spin, one acquire ----------
__device__ __forceinline__ void grid_bar(unsigned* base) {
    __syncthreads();
    if (threadIdx.x == 0) {
        unsigned* flag = base + 15;
        unsigned pg = __hip_atomic_fetch_add(base + (blockIdx.x & 7), 1u,
                                             __ATOMIC_ACQ_REL, __HIP_MEMORY_SCOPE_AGENT);
        if (pg == GRPSZ - 1) {
            unsigned pr = __hip_atomic_fetch_add(base + 8, 1u,
                                                 __ATOMIC_ACQ_REL, __HIP_MEMORY_SCOPE_AGENT);
            if (pr == 7)
                __hip_atomic_store(flag, 1u, __ATOMIC_RELEASE, __HIP_MEMORY_SCOPE_AGENT);
        }
        for (int it = 0; it < (1 << 20); ++it) {  // bounded: wrong answer, not hang
            if (__hip_atomic_load(flag, __ATOMIC_RELAXED, __HIP_MEMORY_SCOPE_AGENT)) break;
            __builtin_amdgcn_s_sleep(2);
        }
        (void)__hip_atomic_load(flag, __ATOMIC_ACQUIRE, __HIP_MEMORY_SCOPE_AGENT);
    }
    __syncthreads();
}

// ---------------- persistent wavefront kernel: all 103 stages -------------
// Weights LDS-resident (128 KiB); h state + x_in in registers; A-panels
// (Hh planes) streamed global->LDS per wave (private 16-row slices, no
// K-loop barriers); 8 waves = 2/SIMD for latency hiding.
__global__ __launch_bounds__(512, 2) void persist_kernel(
    const _Float16* __restrict__ Wrec_h,
    const _Float16* __restrict__ Win_h,
    const float* __restrict__ bc,
    const float* __restrict__ x_in,
    float* __restrict__ Hf,
    _Float16* __restrict__ Hh,
    unsigned* __restrict__ bar) {
    const int b = blockIdx.x;
    const int l  = (b & 7) >> 1;   // (l,mt) -> XCD: the 32 nt-siblings share L2
    const int mt = b & 1;
    const int nt = b >> 3;         // 0..31
    const int row0 = mt * 128, col0 = nt * 32;
    const size_t HSZ = (size_t)BB * NN;

    // 128 KiB weights + 24 KiB A triple-buffer = 152 KiB
    __shared__ __align__(16) _Float16 ldsW[2][NC][32][32];  // [g][chunk][col][32 halves]
    __shared__ __align__(16) _Float16 ldsA[3][8][16][32];   // [buf][wave][row][32 halves]

    const int tid = threadIdx.x;
    const int w = tid >> 6, lane = tid & 63;
    const int lm = lane & 15, kg = lane >> 4;

    // ---- weight panels -> LDS (once). LDS[g][c][col][j] = W[col][c*32 + (j^(col&3))*8..+8]
    {
        const int j   = tid & 3;
        const int col = (tid >> 2) & 31;
        const int pp  = tid >> 7;          // 0..3
        const int ng  = (l > 0) ? 2 : 1;
        for (int g = 0; g < ng; ++g) {
            const _Float16* Wg = (g ? Win_h : Wrec_h) + (size_t)l * NN * NN
                                 + (size_t)(col0 + col) * NN;
            #pragma unroll
            for (int q = 0; q < 8; ++q) {
                int chunk = pp * 8 + q;
                f16x8 v = *(const f16x8*)(Wg + chunk * 32 + ((j ^ (col & 3)) * 8));
                *(f16x8*)(&ldsW[g][chunk][col][j * 8]) = v;
            }
        }
    }

    // ---- per-thread resident state (h in registers; only Hh shadow in memory)
    float bias0 = bc[l * NN + col0 + lm];
    float bias1 = bc[l * NN + col0 + 16 + lm];
    float hreg[2][4] = {};
    float xin[2][4] = {};
    if (l == 0) {
        #pragma unroll
        for (int r = 0; r < 4; ++r) {
            int row = row0 + w * 16 + kg * 4 + r;
            xin[0][r] = x_in[(size_t)row * NN + col0 + lm];
            xin[1][r] = x_in[(size_t)row * NN + col0 + 16 + lm];
        }
    }
    __syncthreads();  // weights visible

    const int arow  = lane >> 2;                 // 0..15
    const int aslot = (lane & 3) ^ (arow & 3);   // rule-#21 involution

    for (int s = 0; s < NSTAGE; ++s) {
        const int t = s - l;
        if (t >= 0 && t < TT) {
            const int src = t & 1, dst = src ^ 1;
            const _Float16* A0 = Hh + ((size_t)src * LL + l) * HSZ;
            const _Float16* A1 = (l > 0) ? Hh + ((size_t)dst * LL + (l - 1)) * HSZ : A0;
            f32x4 acc0 = {0.f, 0.f, 0.f, 0.f};
            f32x4 acc1 = {0.f, 0.f, 0.f, 0.f};
            const int ngem = (l > 0) ? 2 : 1;
            for (int g = 0; g < ngem; ++g) {
                const _Float16* Ap = (g ? A1 : A0)
                    + (size_t)(row0 + w * 16 + arow) * NN + aslot * 8;
                #define AISSUE(c, buf) GLL16(Ap + (c) * 32, &ldsA[buf][w][0][0])
                AISSUE(0, 0); AISSUE(1, 1);
                #pragma unroll
                for (int kk = 0; kk < NC; ++kk) {
                    if (kk < NC - 1) { VMCNT(1); } else { VMCNT(0); }
                    f16x8 a  = *(const f16x8*)(&ldsA[kk % 3][w][lm][(kg ^ (lm & 3)) * 8]);
                    f16x8 b0 = *(const f16x8*)(&ldsW[g][kk][lm][(kg ^ (lm & 3)) * 8]);
                    f16x8 b1 = *(const f16x8*)(&ldsW[g][kk][16 + lm][(kg ^ (lm & 3)) * 8]);
                    if (kk + 2 < NC) AISSUE(kk + 2, (kk + 2) % 3);
                    acc0 = __builtin_amdgcn_mfma_f32_16x16x32_f16(a, b0, acc0, 0, 0, 0);
                    acc1 = __builtin_amdgcn_mfma_f32_16x16x32_f16(a, b1, acc1, 0, 0, 0);
                }
                #undef AISSUE
            }
            // epilogue: h' = h + DT*(-ALPHA*h + sin(pre)); store fp16 shadow
            _Float16* Hhd = Hh + ((size_t)dst * LL + l) * HSZ;
            #pragma unroll
            for (int r = 0; r < 4; ++r) {
                int row = row0 + w * 16 + kg * 4 + r;
                float pre0 = acc0[r] + bias0;
                float pre1 = acc1[r] + bias1;
                if (l == 0) { pre0 += xin[0][r]; pre1 += xin[1][r]; }
                float h0 = hreg[0][r];
                h0 = h0 + DT * (-ALPHA * h0 + __sinf(pre0));
                hreg[0][r] = h0;
                Hhd[(size_t)row * NN + col0 + lm] = (_Float16)h0;
                float h1 = hreg[1][r];
                h1 = h1 + DT * (-ALPHA * h1 + __sinf(pre1));
                hreg[1][r] = h1;
                Hhd[(size_t)row * NN + col0 + 16 + lm] = (_Float16)h1;
            }
        }
        if (s < NSTAGE - 1) grid_bar(bar + s * 16);
    }

    if (l == 3) {  // final fp32 h for out_kernel
        float* Hfl = Hf + (size_t)3 * HSZ;
        #pragma unroll
        for (int r = 0; r < 4; ++r) {
            int row = row0 + w * 16 + kg * 4 + r;
            Hfl[(size_t)row * NN + col0 + lm]      = hreg[0][r];
            Hfl[(size_t)row * NN + col0 + 16 + lm] = hreg[1][r];
        }
    }
}

// ---------------- out = h[3] @ Wo^T + Wo_b  (fp32) ----------------
__global__ __launch_bounds__(256) void out_kernel(
    const float* __restrict__ Hf, const float* __restrict__ Wo_w,
    const float* __restrict__ Wo_b, float* __restrict__ out) {
    const int r = blockIdx.x, tid = threadIdx.x;
    const int lane = tid & 63, w = tid >> 6;
    const float* h = Hf + (size_t)3 * BB * NN + (size_t)r * NN;
    float4 h4 = ((const float4*)h)[tid];
    __shared__ float red[4][16];
    #pragma unroll
    for (int jo = 0; jo < NOUT; ++jo) {
        float4 w4 = ((const float4*)(Wo_w + (size_t)jo * NN))[tid];
        float p = h4.x * w4.x + h4.y * w4.y + h4.z * w4.z + h4.w * w4.w;
        #pragma unroll
        for (int off = 32; off; off >>= 1) p += __shfl_down(p, off);
        if (lane == 0) red[w][jo] = p;
    }
    __syncthreads();
    if (tid < NOUT)
        out[r * NOUT + tid] = red[0][tid] + red[1][tid] + red[2][tid] + red[3][tid] + Wo_b[tid];
}

extern "C" void kernel_launch(void* const* d_in, const int* in_sizes, int n_in,
                              void* d_out, int out_size, void* d_ws, size_t ws_size,
                              hipStream_t stream) {
    const float* X      = (const float*)d_in[0];
    const float* Wi_w   = (const float*)d_in[1];
    const float* Wi_b   = (const float*)d_in[2];
    const float* Win_w  = (const float*)d_in[3];
    const float* Win_b  = (const float*)d_in[4];
    const float* Wrec_w = (const float*)d_in[5];
    const float* Wrec_b = (const float*)d_in[6];
    const float* Wo_w   = (const float*)d_in[7];
    const float* Wo_b   = (const float*)d_in[8];

    char* ws = (char*)d_ws;
    _Float16* Wrec_h = (_Float16*)(ws);                                  // 8 MiB
    _Float16* Win_h  = (_Float16*)(ws + (size_t)(8u  << 20));            // 8 MiB
    float*    Hf     = (float*)   (ws + (size_t)(16u << 20));            // 4 MiB
    _Float16* Hh     = (_Float16*)(ws + (size_t)(20u << 20));            // 4 MiB
    float*    x_in   = (float*)   (ws + (size_t)(24u << 20));            // 1 MiB
    float*    bc     = (float*)   (ws + (size_t)(25u << 20));            // 16 KiB
    _Float16* Xh_hi  = (_Float16*)(ws + (size_t)(25u << 20) + (64u << 10));   // 416 KiB
    _Float16* Xh_lo  = (_Float16*)(ws + (size_t)(25u << 20) + (576u << 10));  // 416 KiB
    unsigned* bar    = (unsigned*)(ws + (size_t)(26u << 20));            // 6.6 KiB
    // Wih hi/lo temporarily alias the Hh region (3.25 MiB <= 4 MiB); Hh is
    // fully memset before persist_kernel reads/writes it.
    _Float16* Wih_hi = (_Float16*)(ws + (size_t)(20u << 20));
    _Float16* Wih_lo = Wih_hi + (size_t)NN * KXP;

    wconv_kernel<<<4096, 256, 0, stream>>>(Wrec_w, Win_w, Wrec_h, Win_h);
    prep_kernel<<<BB + NN, 256, 0, stream>>>(X, Wi_w, Xh_hi, Xh_lo, Wih_hi, Wih_lo);
    bias_kernel<<<16, 256, 0, stream>>>(Win_b, Wrec_b, bc);
    xin_gemm<<<32, 256, 0, stream>>>(Xh_hi, Xh_lo, Wih_hi, Wih_lo, Wi_b, x_in);

    hipMemsetAsync(Hf, 0, (size_t)LL * BB * NN * sizeof(float), stream);
    hipMemsetAsync(Hh, 0, (size_t)2 * LL * BB * NN * sizeof(_Float16), stream);
    hipMemsetAsync(bar, 0, NSTAGE * 16 * sizeof(unsigned), stream);

    persist_kernel<<<GRIDN, 512, 0, stream>>>(Wrec_h, Win_h, bc, x_in, Hf, Hh, bar);

    out_kernel<<<BB, 256, 0, stream>>>(Hf, Wo_w, Wo_b, (float*)d_out);
}